// Round 1
// baseline (123.783 us; speedup 1.0000x reference)
//
#include <hip/hip_runtime.h>

#define HDIM 128
#define BDIM 512

// ---------------- Kernel 1: projection P[r,h] += sum_{k in slice} F[r,k]*W[k,h]
// grid: (B/4, K/ks_len), block: 128 threads (h). Bias NOT added here (folded later).
__global__ __launch_bounds__(128) void proj_kernel(
    const float* __restrict__ F, const float* __restrict__ W,
    float* __restrict__ P, int K, int ks_len)
{
    __shared__ alignas(16) float fbuf[4][HDIM];
    const int h = threadIdx.x;
    const int row0 = blockIdx.x * 4;
    const int k0 = blockIdx.y * ks_len;

    float acc0 = 0.f, acc1 = 0.f, acc2 = 0.f, acc3 = 0.f;

    for (int c0 = k0; c0 < k0 + ks_len; c0 += HDIM) {
        __syncthreads();
        #pragma unroll
        for (int r = 0; r < 4; ++r)
            fbuf[r][h] = F[(size_t)(row0 + r) * K + c0 + h];
        __syncthreads();

        const float4* fb0 = (const float4*)fbuf[0];
        const float4* fb1 = (const float4*)fbuf[1];
        const float4* fb2 = (const float4*)fbuf[2];
        const float4* fb3 = (const float4*)fbuf[3];

        #pragma unroll 4
        for (int c4 = 0; c4 < HDIM / 4; ++c4) {
            float4 f0 = fb0[c4], f1 = fb1[c4], f2 = fb2[c4], f3 = fb3[c4];
            const float* wp = W + (size_t)(c0 + 4 * c4) * HDIM + h;
            float w0 = wp[0];
            float w1 = wp[HDIM];
            float w2 = wp[2 * HDIM];
            float w3 = wp[3 * HDIM];
            acc0 = fmaf(f0.x, w0, fmaf(f0.y, w1, fmaf(f0.z, w2, fmaf(f0.w, w3, acc0))));
            acc1 = fmaf(f1.x, w0, fmaf(f1.y, w1, fmaf(f1.z, w2, fmaf(f1.w, w3, acc1))));
            acc2 = fmaf(f2.x, w0, fmaf(f2.y, w1, fmaf(f2.z, w2, fmaf(f2.w, w3, acc2))));
            acc3 = fmaf(f3.x, w0, fmaf(f3.y, w1, fmaf(f3.z, w2, fmaf(f3.w, w3, acc3))));
        }
    }
    atomicAdd(&P[(size_t)(row0 + 0) * HDIM + h], acc0);
    atomicAdd(&P[(size_t)(row0 + 1) * HDIM + h], acc1);
    atomicAdd(&P[(size_t)(row0 + 2) * HDIM + h], acc2);
    atomicAdd(&P[(size_t)(row0 + 3) * HDIM + h], acc3);
}

// ---------------- Kernel 2: U = (P+b) @ W1[:H] + b1 ; V = (P+b) @ W1[H:]
// grid: (B/4, 2 feature sets), block: 128 threads.
__global__ __launch_bounds__(128) void uv_kernel(
    const float* __restrict__ Pt, const float* __restrict__ Ps,
    const float* __restrict__ bt, const float* __restrict__ bs,
    const float* __restrict__ W1, const float* __restrict__ b1,
    float* __restrict__ Ut, float* __restrict__ Vt,
    float* __restrict__ Us, float* __restrict__ Vs)
{
    const float* P; const float* bb; float* U; float* V;
    if (blockIdx.y == 0) { P = Pt; bb = bt; U = Ut; V = Vt; }
    else                 { P = Ps; bb = bs; U = Us; V = Vs; }

    __shared__ alignas(16) float fbuf[4][HDIM];
    const int h = threadIdx.x;
    const int row0 = blockIdx.x * 4;

    #pragma unroll
    for (int r = 0; r < 4; ++r)
        fbuf[r][h] = P[(size_t)(row0 + r) * HDIM + h] + bb[h];
    __syncthreads();

    float au[4] = {0.f, 0.f, 0.f, 0.f};
    float av[4] = {0.f, 0.f, 0.f, 0.f};

    const float4* fb0 = (const float4*)fbuf[0];
    const float4* fb1 = (const float4*)fbuf[1];
    const float4* fb2 = (const float4*)fbuf[2];
    const float4* fb3 = (const float4*)fbuf[3];

    #pragma unroll 2
    for (int c4 = 0; c4 < HDIM / 4; ++c4) {
        float f[4][4];
        *(float4*)f[0] = fb0[c4];
        *(float4*)f[1] = fb1[c4];
        *(float4*)f[2] = fb2[c4];
        *(float4*)f[3] = fb3[c4];
        #pragma unroll
        for (int q = 0; q < 4; ++q) {
            int k = 4 * c4 + q;
            float wu = W1[(size_t)k * HDIM + h];
            float wv = W1[(size_t)(HDIM + k) * HDIM + h];
            #pragma unroll
            for (int r = 0; r < 4; ++r) {
                au[r] = fmaf(f[r][q], wu, au[r]);
                av[r] = fmaf(f[r][q], wv, av[r]);
            }
        }
    }

    float bb1 = b1[h];
    #pragma unroll
    for (int r = 0; r < 4; ++r) {
        U[(size_t)(row0 + r) * HDIM + h] = au[r] + bb1;
        V[(size_t)(row0 + r) * HDIM + h] = av[r];
    }
}

// ---------------- Kernel 3: pairwise relations + MSE accumulation
// grid: (B/16, B/16), block: (16,16). One thread = one (i,j) pair.
__global__ __launch_bounds__(256) void pair_kernel(
    const float* __restrict__ Ut, const float* __restrict__ Vt,
    const float* __restrict__ Us, const float* __restrict__ Vs,
    const float* __restrict__ W2, const float* __restrict__ b2,
    float* __restrict__ out)
{
    // row stride 33 float4 (=132 floats) to break bank conflicts on broadcast rows
    __shared__ alignas(16) float4 tUt[16 * 33];
    __shared__ alignas(16) float4 tVt[16 * 33];
    __shared__ alignas(16) float4 tUs[16 * 33];
    __shared__ alignas(16) float4 tVs[16 * 33];
    __shared__ alignas(16) float4 w2s[32];
    __shared__ float red[256];

    const int tx = threadIdx.x, ty = threadIdx.y;
    const int tid = ty * 16 + tx;
    const int i0 = blockIdx.y * 16, j0 = blockIdx.x * 16;

    const float4* Ut4 = (const float4*)Ut;
    const float4* Vt4 = (const float4*)Vt;
    const float4* Us4 = (const float4*)Us;
    const float4* Vs4 = (const float4*)Vs;

    #pragma unroll
    for (int it = 0; it < 2; ++it) {
        int fi = tid + 256 * it;          // 0..511
        int r = fi >> 5, c = fi & 31;     // 16 rows x 32 float4
        tUt[r * 33 + c] = Ut4[(size_t)(i0 + r) * 32 + c];
        tVt[r * 33 + c] = Vt4[(size_t)(j0 + r) * 32 + c];
        tUs[r * 33 + c] = Us4[(size_t)(i0 + r) * 32 + c];
        tVs[r * 33 + c] = Vs4[(size_t)(j0 + r) * 32 + c];
    }
    if (tid < 32) w2s[tid] = ((const float4*)W2)[tid];
    __syncthreads();

    const float4* ut = &tUt[ty * 33];
    const float4* vt = &tVt[tx * 33];
    const float4* us = &tUs[ty * 33];
    const float4* vs = &tVs[tx * 33];

    float st = 0.f, ss = 0.f;
    #pragma unroll 8
    for (int h4 = 0; h4 < 32; ++h4) {
        float4 w = w2s[h4];
        float4 a = ut[h4], b = vt[h4];
        st += fmaxf(a.x + b.x, 0.f) * w.x + fmaxf(a.y + b.y, 0.f) * w.y
            + fmaxf(a.z + b.z, 0.f) * w.z + fmaxf(a.w + b.w, 0.f) * w.w;
        float4 c = us[h4], d = vs[h4];
        ss += fmaxf(c.x + d.x, 0.f) * w.x + fmaxf(c.y + d.y, 0.f) * w.y
            + fmaxf(c.z + d.z, 0.f) * w.z + fmaxf(c.w + d.w, 0.f) * w.w;
    }

    const float b2v = b2[0];
    const int i = i0 + ty, j = j0 + tx;
    float dd;
    if (i == j) {
        dd = 0.f;   // diagonal zeroed in both rels
    } else {
        float tr = 1.f / (1.f + __expf(-(st + b2v)));
        float sr = 1.f / (1.f + __expf(-(ss + b2v)));
        float d = sr - tr;
        dd = d * d;
    }
    red[tid] = dd;
    __syncthreads();
    #pragma unroll
    for (int s = 128; s > 0; s >>= 1) {
        if (tid < s) red[tid] += red[tid + s];
        __syncthreads();
    }
    if (tid == 0)
        atomicAdd(out, red[0] * (1.0f / ((float)BDIM * (float)BDIM)));
}

extern "C" void kernel_launch(void* const* d_in, const int* in_sizes, int n_in,
                              void* d_out, int out_size, void* d_ws, size_t ws_size,
                              hipStream_t stream) {
    const float* teacher = (const float*)d_in[0];   // [512,2048]
    const float* student = (const float*)d_in[1];   // [512,768]
    const float* Wt = (const float*)d_in[2];        // [2048,128]
    const float* bt = (const float*)d_in[3];        // [128]
    const float* Ws = (const float*)d_in[4];        // [768,128]
    const float* bs = (const float*)d_in[5];        // [128]
    const float* W1 = (const float*)d_in[6];        // [256,128]
    const float* b1 = (const float*)d_in[7];        // [128]
    const float* W2 = (const float*)d_in[8];        // [128,1]
    const float* b2 = (const float*)d_in[9];        // [1]
    float* out = (float*)d_out;

    float* ws = (float*)d_ws;
    const size_t M = (size_t)BDIM * HDIM;           // 65536 floats
    float* Pt = ws + 0 * M;
    float* Ps = ws + 1 * M;
    float* Ut = ws + 2 * M;
    float* Vt = ws + 3 * M;
    float* Us = ws + 4 * M;
    float* Vs = ws + 5 * M;

    // zero the atomic accumulation targets
    hipMemsetAsync(Pt, 0, 2 * M * sizeof(float), stream);
    hipMemsetAsync(d_out, 0, sizeof(float), stream);

    // teacher: K=2048, 8 k-slices of 256 -> 1024 blocks
    proj_kernel<<<dim3(BDIM / 4, 8), 128, 0, stream>>>(teacher, Wt, Pt, 2048, 256);
    // student: K=768, 3 k-slices of 256 -> 384 blocks
    proj_kernel<<<dim3(BDIM / 4, 3), 128, 0, stream>>>(student, Ws, Ps, 768, 256);

    uv_kernel<<<dim3(BDIM / 4, 2), 128, 0, stream>>>(Pt, Ps, bt, bs, W1, b1,
                                                     Ut, Vt, Us, Vs);

    pair_kernel<<<dim3(BDIM / 16, BDIM / 16), dim3(16, 16), 0, stream>>>(
        Ut, Vt, Us, Vs, W2, b2, out);
}

// Round 2
// 111.498 us; speedup vs baseline: 1.1102x; 1.1102x over previous
//
#include <hip/hip_runtime.h>

#define HDIM 128
#define BDIM 512
#define PM (BDIM * HDIM)   // 65536 floats per [B,H] matrix

// ---------------- Kernel 1: projection partials, no atomics.
// grid: (B/4, 11): y<8 -> teacher slice y (K=2048, 8 slices of 256)
//                  y>=8 -> student slice y-8 (K=768, 3 slices of 256)
// block: 128 threads (h). Writes Ppart[slice][row][h] with plain stores.
__global__ __launch_bounds__(128) void proj_kernel(
    const float* __restrict__ Ft, const float* __restrict__ Fs,
    const float* __restrict__ Wt, const float* __restrict__ Ws,
    float* __restrict__ Ppt, float* __restrict__ Pps)
{
    const float* F; const float* W; float* P; int K, slice;
    if (blockIdx.y < 8) { F = Ft; W = Wt; P = Ppt; K = 2048; slice = blockIdx.y; }
    else                { F = Fs; W = Ws; P = Pps; K = 768;  slice = blockIdx.y - 8; }

    __shared__ alignas(16) float fbuf[4][HDIM];
    const int h = threadIdx.x;
    const int row0 = blockIdx.x * 4;
    const int k0 = slice * 256;

    float acc0 = 0.f, acc1 = 0.f, acc2 = 0.f, acc3 = 0.f;

    for (int c0 = k0; c0 < k0 + 256; c0 += HDIM) {
        __syncthreads();
        #pragma unroll
        for (int r = 0; r < 4; ++r)
            fbuf[r][h] = F[(size_t)(row0 + r) * K + c0 + h];
        __syncthreads();

        const float4* fb0 = (const float4*)fbuf[0];
        const float4* fb1 = (const float4*)fbuf[1];
        const float4* fb2 = (const float4*)fbuf[2];
        const float4* fb3 = (const float4*)fbuf[3];

        #pragma unroll 4
        for (int c4 = 0; c4 < HDIM / 4; ++c4) {
            float4 f0 = fb0[c4], f1 = fb1[c4], f2 = fb2[c4], f3 = fb3[c4];
            const float* wp = W + (size_t)(c0 + 4 * c4) * HDIM + h;
            float w0 = wp[0];
            float w1 = wp[HDIM];
            float w2 = wp[2 * HDIM];
            float w3 = wp[3 * HDIM];
            acc0 = fmaf(f0.x, w0, fmaf(f0.y, w1, fmaf(f0.z, w2, fmaf(f0.w, w3, acc0))));
            acc1 = fmaf(f1.x, w0, fmaf(f1.y, w1, fmaf(f1.z, w2, fmaf(f1.w, w3, acc1))));
            acc2 = fmaf(f2.x, w0, fmaf(f2.y, w1, fmaf(f2.z, w2, fmaf(f2.w, w3, acc2))));
            acc3 = fmaf(f3.x, w0, fmaf(f3.y, w1, fmaf(f3.z, w2, fmaf(f3.w, w3, acc3))));
        }
    }
    float* Prow = P + (size_t)slice * PM + (size_t)row0 * HDIM + h;
    Prow[0 * HDIM] = acc0;
    Prow[1 * HDIM] = acc1;
    Prow[2 * HDIM] = acc2;
    Prow[3 * HDIM] = acc3;
}

// ---------------- Kernel 2: sum slices + bias, then U = P@W1a + b1, V = P@W1b
// grid: (B/4, 2), block: 128 threads.
__global__ __launch_bounds__(128) void uv_kernel(
    const float* __restrict__ Ppt, const float* __restrict__ Pps,
    const float* __restrict__ bt, const float* __restrict__ bs,
    const float* __restrict__ W1, const float* __restrict__ b1,
    float* __restrict__ Ut, float* __restrict__ Vt,
    float* __restrict__ Us, float* __restrict__ Vs)
{
    const float* Pp; const float* bb; float* U; float* V; int ns;
    if (blockIdx.y == 0) { Pp = Ppt; bb = bt; U = Ut; V = Vt; ns = 8; }
    else                 { Pp = Pps; bb = bs; U = Us; V = Vs; ns = 3; }

    __shared__ alignas(16) float fbuf[4][HDIM];
    const int h = threadIdx.x;
    const int row0 = blockIdx.x * 4;

    #pragma unroll
    for (int r = 0; r < 4; ++r) {
        float acc = bb[h];
        for (int s = 0; s < ns; ++s)
            acc += Pp[(size_t)s * PM + (size_t)(row0 + r) * HDIM + h];
        fbuf[r][h] = acc;
    }
    __syncthreads();

    float au[4] = {0.f, 0.f, 0.f, 0.f};
    float av[4] = {0.f, 0.f, 0.f, 0.f};

    const float4* fb0 = (const float4*)fbuf[0];
    const float4* fb1 = (const float4*)fbuf[1];
    const float4* fb2 = (const float4*)fbuf[2];
    const float4* fb3 = (const float4*)fbuf[3];

    #pragma unroll 2
    for (int c4 = 0; c4 < HDIM / 4; ++c4) {
        float f[4][4];
        *(float4*)f[0] = fb0[c4];
        *(float4*)f[1] = fb1[c4];
        *(float4*)f[2] = fb2[c4];
        *(float4*)f[3] = fb3[c4];
        #pragma unroll
        for (int q = 0; q < 4; ++q) {
            int k = 4 * c4 + q;
            float wu = W1[(size_t)k * HDIM + h];
            float wv = W1[(size_t)(HDIM + k) * HDIM + h];
            #pragma unroll
            for (int r = 0; r < 4; ++r) {
                au[r] = fmaf(f[r][q], wu, au[r]);
                av[r] = fmaf(f[r][q], wv, av[r]);
            }
        }
    }

    float bb1 = b1[h];
    #pragma unroll
    for (int r = 0; r < 4; ++r) {
        U[(size_t)(row0 + r) * HDIM + h] = au[r] + bb1;
        V[(size_t)(row0 + r) * HDIM + h] = av[r];
    }
}

// ---------------- Kernel 3: pairwise relations, 2x2 register blocking.
// grid: (16,16) -> 32x32 pair tiles. block (16,16).
// Thread (tx,ty) computes pairs (i0+ty+16a, j0+tx+16b), a,b in {0,1}.
// h processed in two 64-wide chunks to fit LDS. Writes one partial per block.
__global__ __launch_bounds__(256) void pair_kernel(
    const float* __restrict__ Ut, const float* __restrict__ Vt,
    const float* __restrict__ Us, const float* __restrict__ Vs,
    const float* __restrict__ W2, const float* __restrict__ b2,
    float* __restrict__ partial)
{
    // 32 rows x 16 float4 per chunk, stride 17 to break conflicts on V reads
    __shared__ alignas(16) float4 tUt[32 * 17];
    __shared__ alignas(16) float4 tVt[32 * 17];
    __shared__ alignas(16) float4 tUs[32 * 17];
    __shared__ alignas(16) float4 tVs[32 * 17];
    __shared__ alignas(16) float4 w2s[32];
    __shared__ float red[256];

    const int tx = threadIdx.x, ty = threadIdx.y;
    const int tid = ty * 16 + tx;
    const int i0 = blockIdx.y * 32, j0 = blockIdx.x * 32;

    const float4* Ut4 = (const float4*)Ut;
    const float4* Vt4 = (const float4*)Vt;
    const float4* Us4 = (const float4*)Us;
    const float4* Vs4 = (const float4*)Vs;

    if (tid < 32) w2s[tid] = ((const float4*)W2)[tid];

    float aT[2][2] = {{0.f, 0.f}, {0.f, 0.f}};
    float aS[2][2] = {{0.f, 0.f}, {0.f, 0.f}};

    for (int half = 0; half < 2; ++half) {
        const int c0 = half * 16;
        __syncthreads();   // protect LDS reuse across halves (no-op cost on half 0)
        #pragma unroll
        for (int it = 0; it < 2; ++it) {
            int fi = tid + 256 * it;           // 0..511
            int r = fi >> 4, c = fi & 15;      // 32 rows x 16 float4
            tUt[r * 17 + c] = Ut4[(size_t)(i0 + r) * 32 + c0 + c];
            tVt[r * 17 + c] = Vt4[(size_t)(j0 + r) * 32 + c0 + c];
            tUs[r * 17 + c] = Us4[(size_t)(i0 + r) * 32 + c0 + c];
            tVs[r * 17 + c] = Vs4[(size_t)(j0 + r) * 32 + c0 + c];
        }
        __syncthreads();

        #pragma unroll 4
        for (int h4 = 0; h4 < 16; ++h4) {
            float4 w = w2s[c0 + h4];
            float4 u[2], v[2], p[2], q[2];
            u[0] = tUt[ty * 17 + h4];        u[1] = tUt[(ty + 16) * 17 + h4];
            v[0] = tVt[tx * 17 + h4];        v[1] = tVt[(tx + 16) * 17 + h4];
            p[0] = tUs[ty * 17 + h4];        p[1] = tUs[(ty + 16) * 17 + h4];
            q[0] = tVs[tx * 17 + h4];        q[1] = tVs[(tx + 16) * 17 + h4];
            #pragma unroll
            for (int a = 0; a < 2; ++a)
                #pragma unroll
                for (int b = 0; b < 2; ++b) {
                    aT[a][b] = fmaf(fmaxf(u[a].x + v[b].x, 0.f), w.x,
                               fmaf(fmaxf(u[a].y + v[b].y, 0.f), w.y,
                               fmaf(fmaxf(u[a].z + v[b].z, 0.f), w.z,
                               fmaf(fmaxf(u[a].w + v[b].w, 0.f), w.w, aT[a][b]))));
                    aS[a][b] = fmaf(fmaxf(p[a].x + q[b].x, 0.f), w.x,
                               fmaf(fmaxf(p[a].y + q[b].y, 0.f), w.y,
                               fmaf(fmaxf(p[a].z + q[b].z, 0.f), w.z,
                               fmaf(fmaxf(p[a].w + q[b].w, 0.f), w.w, aS[a][b]))));
                }
        }
    }

    const float b2v = b2[0];
    float local = 0.f;
    #pragma unroll
    for (int a = 0; a < 2; ++a)
        #pragma unroll
        for (int b = 0; b < 2; ++b) {
            int i = i0 + ty + 16 * a;
            int j = j0 + tx + 16 * b;
            if (i != j) {
                float tr = 1.f / (1.f + __expf(-(aT[a][b] + b2v)));
                float sr = 1.f / (1.f + __expf(-(aS[a][b] + b2v)));
                float d = sr - tr;
                local = fmaf(d, d, local);
            }
        }

    red[tid] = local;
    __syncthreads();
    #pragma unroll
    for (int s = 128; s > 0; s >>= 1) {
        if (tid < s) red[tid] += red[tid + s];
        __syncthreads();
    }
    if (tid == 0)
        partial[blockIdx.y * 16 + blockIdx.x] = red[0];
}

// ---------------- Kernel 4: final 256-way sum, one wave.
__global__ __launch_bounds__(64) void finish_kernel(
    const float* __restrict__ partial, float* __restrict__ out)
{
    const int l = threadIdx.x;
    float v = 0.f;
    #pragma unroll
    for (int i = 0; i < 4; ++i) v += partial[l + 64 * i];
    #pragma unroll
    for (int off = 32; off > 0; off >>= 1) v += __shfl_down(v, off, 64);
    if (l == 0) out[0] = v * (1.0f / ((float)BDIM * (float)BDIM));
}

extern "C" void kernel_launch(void* const* d_in, const int* in_sizes, int n_in,
                              void* d_out, int out_size, void* d_ws, size_t ws_size,
                              hipStream_t stream) {
    const float* teacher = (const float*)d_in[0];   // [512,2048]
    const float* student = (const float*)d_in[1];   // [512,768]
    const float* Wt = (const float*)d_in[2];        // [2048,128]
    const float* bt = (const float*)d_in[3];        // [128]
    const float* Ws = (const float*)d_in[4];        // [768,128]
    const float* bs = (const float*)d_in[5];        // [128]
    const float* W1 = (const float*)d_in[6];        // [256,128]
    const float* b1 = (const float*)d_in[7];        // [128]
    const float* W2 = (const float*)d_in[8];        // [128,1]
    const float* b2 = (const float*)d_in[9];        // [1]
    float* out = (float*)d_out;

    float* ws = (float*)d_ws;
    float* Ppt = ws;                      // [8][512][128]
    float* Pps = Ppt + 8 * PM;            // [3][512][128]
    float* Ut  = Pps + 3 * PM;
    float* Vt  = Ut + PM;
    float* Us  = Vt + PM;
    float* Vs  = Us + PM;
    float* partial = Vs + PM;             // [256]

    proj_kernel<<<dim3(BDIM / 4, 11), 128, 0, stream>>>(teacher, student, Wt, Ws, Ppt, Pps);

    uv_kernel<<<dim3(BDIM / 4, 2), 128, 0, stream>>>(Ppt, Pps, bt, bs, W1, b1,
                                                     Ut, Vt, Us, Vs);

    pair_kernel<<<dim3(16, 16), dim3(16, 16), 0, stream>>>(
        Ut, Vt, Us, Vs, W2, b2, partial);

    finish_kernel<<<1, 64, 0, stream>>>(partial, out);
}